// Round 1
// baseline (201.258 us; speedup 1.0000x reference)
//
#include <hip/hip_runtime.h>
#include <hip/hip_bf16.h>

typedef __bf16 bf16_t;
typedef __bf16 bf16x8 __attribute__((ext_vector_type(8)));
typedef float f32x4 __attribute__((ext_vector_type(4)));

#define BATCH 4
#define SEQ 4096
#define FIN 33
#define DIM 64

// ---------------- Kernel 1: q/k affine projections (fp32 math, bf16 store) ----------------
__global__ __launch_bounds__(256) void qk_proj_kernel(
    const float* __restrict__ x, const float* __restrict__ Wq,
    const float* __restrict__ bq, const float* __restrict__ Wk,
    const float* __restrict__ bk,
    bf16_t* __restrict__ qout, bf16_t* __restrict__ kout)
{
    __shared__ float sWq[FIN * DIM];
    __shared__ float sWk[FIN * DIM];
    __shared__ float sb[2 * DIM];
    const int t = threadIdx.x;
    for (int i = t; i < FIN * DIM; i += 256) { sWq[i] = Wq[i]; sWk[i] = Wk[i]; }
    if (t < DIM) { sb[t] = bq[t]; sb[DIM + t] = bk[t]; }
    __syncthreads();

    const int row = blockIdx.x * 4 + (t >> 6);   // [0, 16384)
    const int d   = t & 63;
    const float* xr = x + (size_t)row * FIN;
    float qacc = sb[d], kacc = sb[DIM + d];
#pragma unroll
    for (int f = 0; f < FIN; ++f) {
        const float xv = xr[f];                   // wave-uniform -> broadcast fetch
        qacc += xv * sWq[f * DIM + d];
        kacc += xv * sWk[f * DIM + d];
    }
    qout[(size_t)row * DIM + d] = (bf16_t)qacc;
    kout[(size_t)row * DIM + d] = (bf16_t)kacc;
}

// ---------------- Kernel 2: fused QK^T + row-max-normalized softmax ----------------
// WG = 16 rows of one batch, 4 waves, each wave owns 1024 cols.
// 3 recompute passes over cols: (1) row max, (2) Z = sum exp(s/M - 1), (3) write p.
__device__ __forceinline__ f32x4 tile_score(const bf16_t* kb, bf16x8 a0, bf16x8 a1)
{
    bf16x8 b0 = *reinterpret_cast<const bf16x8*>(kb);
    bf16x8 b1 = *reinterpret_cast<const bf16x8*>(kb + 32);
    f32x4 acc = {0.f, 0.f, 0.f, 0.f};
    acc = __builtin_amdgcn_mfma_f32_16x16x32_bf16(a0, b0, acc, 0, 0, 0);
    acc = __builtin_amdgcn_mfma_f32_16x16x32_bf16(a1, b1, acc, 0, 0, 0);
    return acc;
}

__global__ __launch_bounds__(256) void attn_kernel(
    const bf16_t* __restrict__ qg, const bf16_t* __restrict__ kg,
    float* __restrict__ out)
{
    const int wg  = blockIdx.x;        // 0..1023
    const int b   = wg >> 8;           // batch
    const int r0  = (wg & 255) << 4;   // 16-row block within batch
    const int t   = threadIdx.x;
    const int w   = t >> 6;            // wave 0..3
    const int l   = t & 63;
    const int lr  = l & 15;            // A-row / B-col / D-col lane index
    const int kg4 = l >> 4;            // k-group; D rows kg4*4 .. +3

    const bf16_t* qbase = qg + (size_t)(b * SEQ + r0) * DIM;
    const bf16_t* kbase = kg + (size_t)b * SEQ * DIM;

    // A fragments (constant across the col loop): q[row = lr][k = kg4*8 .. +8]
    const bf16x8 a0 = *reinterpret_cast<const bf16x8*>(qbase + lr * DIM + kg4 * 8);
    const bf16x8 a1 = *reinterpret_cast<const bf16x8*>(qbase + lr * DIM + 32 + kg4 * 8);

    const int col0 = w << 10;          // 1024 cols per wave
    const bf16_t* kw = kbase + (size_t)(col0 + lr) * DIM + kg4 * 8;

    __shared__ float redM[4][16];
    __shared__ float redZ[4][16];

    // ---- pass 1: row max ----
    float vmax[4] = {-3.4e38f, -3.4e38f, -3.4e38f, -3.4e38f};
#pragma unroll 2
    for (int ct = 0; ct < 64; ++ct) {
        f32x4 acc = tile_score(kw + (size_t)ct * 16 * DIM, a0, a1);
#pragma unroll
        for (int j = 0; j < 4; ++j) vmax[j] = fmaxf(vmax[j], acc[j]);
    }
#pragma unroll
    for (int m = 1; m < 16; m <<= 1) {
#pragma unroll
        for (int j = 0; j < 4; ++j) vmax[j] = fmaxf(vmax[j], __shfl_xor(vmax[j], m, 64));
    }
    if (lr == 0) {
#pragma unroll
        for (int j = 0; j < 4; ++j) redM[w][kg4 * 4 + j] = vmax[j];
    }
    __syncthreads();
    float invM[4];
#pragma unroll
    for (int j = 0; j < 4; ++j) {
        const int r = kg4 * 4 + j;
        const float m = fmaxf(fmaxf(redM[0][r], redM[1][r]), fmaxf(redM[2][r], redM[3][r]));
        invM[j] = 1.0f / m;            // TEMPERATURE = 1.0 folded in here
    }

    // ---- pass 2: Z = sum exp(s/M - 1) ----
    float vsum[4] = {0.f, 0.f, 0.f, 0.f};
#pragma unroll 2
    for (int ct = 0; ct < 64; ++ct) {
        f32x4 acc = tile_score(kw + (size_t)ct * 16 * DIM, a0, a1);
#pragma unroll
        for (int j = 0; j < 4; ++j) vsum[j] += __expf(acc[j] * invM[j] - 1.0f);
    }
#pragma unroll
    for (int m = 1; m < 16; m <<= 1) {
#pragma unroll
        for (int j = 0; j < 4; ++j) vsum[j] += __shfl_xor(vsum[j], m, 64);
    }
    if (lr == 0) {
#pragma unroll
        for (int j = 0; j < 4; ++j) redZ[w][kg4 * 4 + j] = vsum[j];
    }
    __syncthreads();
    float invZ[4];
#pragma unroll
    for (int j = 0; j < 4; ++j) {
        const int r = kg4 * 4 + j;
        invZ[j] = 1.0f / (redZ[0][r] + redZ[1][r] + redZ[2][r] + redZ[3][r]);
    }

    // ---- pass 3: write p = exp(s/M - 1) * invZ ----
    float* orow = out + (size_t)(b * SEQ + r0 + kg4 * 4) * SEQ + col0 + lr;
#pragma unroll 2
    for (int ct = 0; ct < 64; ++ct) {
        f32x4 acc = tile_score(kw + (size_t)ct * 16 * DIM, a0, a1);
#pragma unroll
        for (int j = 0; j < 4; ++j) {
            const float p = __expf(acc[j] * invM[j] - 1.0f) * invZ[j];
            orow[(size_t)j * SEQ + ct * 16] = p;
        }
    }
}

extern "C" void kernel_launch(void* const* d_in, const int* in_sizes, int n_in,
                              void* d_out, int out_size, void* d_ws, size_t ws_size,
                              hipStream_t stream)
{
    const float* x  = (const float*)d_in[0];
    const float* Wq = (const float*)d_in[1];
    const float* bq = (const float*)d_in[2];
    const float* Wk = (const float*)d_in[3];
    const float* bk = (const float*)d_in[4];
    float* out = (float*)d_out;

    bf16_t* qws = (bf16_t*)d_ws;
    bf16_t* kws = qws + (size_t)BATCH * SEQ * DIM;

    qk_proj_kernel<<<(BATCH * SEQ) / 4, 256, 0, stream>>>(x, Wq, bq, Wk, bk, qws, kws);
    attn_kernel<<<BATCH * (SEQ / 16), 256, 0, stream>>>(qws, kws, out);
}